// Round 16
// baseline (201.850 us; speedup 1.0000x reference)
//
#include <hip/hip_runtime.h>
#include <cstdint>

#define DIM_ 768
#define H_ 6
#define HD_ 128
#define NB_ 4
#define SEQ_ 2048
#define TOK_ (NB_*SEQ_)
#define OUT3_ (3*DIM_)
#define L2E 1.4426950408889634f

typedef __bf16 bf16;
typedef __bf16 bf16x4 __attribute__((ext_vector_type(4)));
typedef __bf16 bf16x8 __attribute__((ext_vector_type(8)));
typedef float f32x4 __attribute__((ext_vector_type(4)));
typedef float f32x16 __attribute__((ext_vector_type(16)));
typedef unsigned int u32;
typedef u32 u32x4 __attribute__((ext_vector_type(4)));

__device__ __forceinline__ void gload16(const void* g, void* lds) {
  __builtin_amdgcn_global_load_lds((const __attribute__((address_space(1))) void*)g,
                                   (__attribute__((address_space(3))) void*)lds,
                                   16, 0, 0);
}

// ---------------- fp32 -> bf16 convert ----------------
__global__ void convert_kernel(const float* __restrict__ in, bf16* __restrict__ out, int n) {
  int i = (blockIdx.x * 256 + threadIdx.x) * 4;
  if (i >= n) return;
  float4 v = *reinterpret_cast<const float4*>(in + i);
  bf16x4 o = { (bf16)v.x, (bf16)v.y, (bf16)v.z, (bf16)v.w };
  *reinterpret_cast<bf16x4*>(out + i) = o;
}

// ---------------- mask kernel ----------------
__global__ void mask_kernel(const float* __restrict__ latency,
                            const float* __restrict__ rw,
                            const float* __restrict__ rb,
                            const float* __restrict__ g1,
                            const float* __restrict__ g2,
                            float* __restrict__ mask6) {
  int i = threadIdx.x;
  if (i < 6) {
    int j = (i < 4) ? 0 : (i - 3);
    float logit = rw[j] * latency[0] + rb[j];
    float z = (logit + g1[j] - g2[j]) / 5.0f;
    float ys = 1.0f / (1.0f + expf(-z));
    float yh = ys > 0.5f ? 1.0f : 0.0f;
    mask6[i] = (yh - ys) + ys;   // exactly 0.0f when gated off
  }
}

// Fragment-major layouts (elements):
//  QF idx = (((bh*64 + n/32)*8 + kc)*512) + ((d>>3&1)*32 + n%32)*8 + d%8   [kc=d>>4]
//  KF 32-key tile jj: contiguous 4096 elems at bh*262144 + jj*4096 (+ kc*512 + lane*8)
//  VF 32-key tile jj: contiguous 4096 elems at bh*262144 + jj*4096 (+ (ks*4+df)*512 + lane*8)

// ---------------- QKV GEMM (bf16 MFMA): qkv = x @ qkv_w^T + b ----------------
__global__ __launch_bounds__(256)
void qkv_gemm(const bf16* __restrict__ A, const bf16* __restrict__ W,
              const float* __restrict__ bias, const float* __restrict__ mask6,
              bf16* __restrict__ q, bf16* __restrict__ k, bf16* __restrict__ vt) {
  __shared__ bf16 As[128 * 32];
  __shared__ bf16 Bs[128 * 32];
  __shared__ bf16 FragS[8192];   // 16 KB fragment-staging for q/k epilogue
  const int tid = threadIdx.x;
  const int l = tid & 63, w = tid >> 6;
  const int lr = l & 15, lg = l >> 4;
  const int wm = w >> 1, wn = w & 1;
  const int tm = blockIdx.y * 128;
  const int on = blockIdx.x * 128;

  // head gating: block-uniform early exit
  const int sblk = (on < DIM_) ? 0 : (on < 2 * DIM_ ? 1 : 2);
  const int hblk = (on - sblk * DIM_) >> 7;
  if (mask6[hblk] == 0.0f) return;

  f32x4 acc[4][4];
#pragma unroll
  for (int i = 0; i < 4; ++i)
#pragma unroll
    for (int j = 0; j < 4; ++j) acc[i][j] = f32x4{0.f, 0.f, 0.f, 0.f};

  for (int k0 = 0; k0 < DIM_; k0 += 32) {
    __syncthreads();
#pragma unroll
    for (int u = 0; u < 2; ++u) {
      int row = w * 32 + u * 16 + (l >> 2);
      int cb = l & 3;
      gload16(A + (size_t)(tm + row) * DIM_ + k0 + cb * 8, As + (w * 32 + u * 16) * 32);
      gload16(W + (size_t)(on + row) * DIM_ + k0 + cb * 8, Bs + (w * 32 + u * 16) * 32);
    }
    __syncthreads();
    bf16x8 af[4], bfr[4];
#pragma unroll
    for (int i = 0; i < 4; ++i)
      af[i] = *reinterpret_cast<const bf16x8*>(As + (wm * 64 + i * 16 + lr) * 32 + lg * 8);
#pragma unroll
    for (int j = 0; j < 4; ++j)
      bfr[j] = *reinterpret_cast<const bf16x8*>(Bs + (wn * 64 + j * 16 + lr) * 32 + lg * 8);
#pragma unroll
    for (int i = 0; i < 4; ++i)
#pragma unroll
      for (int j = 0; j < 4; ++j)
        acc[i][j] = __builtin_amdgcn_mfma_f32_16x16x32_bf16(af[i], bfr[j], acc[i][j], 0, 0, 0);
  }

  if (on < 2 * DIM_) {
    // q/k: build fragment-major 64-row tiles in LDS, store 16B-coalesced
    const int s = sblk;
    const float scale = 0.08838834764831845f * L2E;
    const int n0 = tm & 2047;
    const int bb = tm >> 11;
    const int bhh = bb * H_ + hblk;
    bf16* dstbase = (s == 0) ? q : k;
    for (int pass = 0; pass < 2; ++pass) {
      __syncthreads();
      if (wm == pass) {
#pragma unroll
        for (int i = 0; i < 4; ++i) {
#pragma unroll
          for (int j = 0; j < 4; ++j) {
            int dd = wn * 64 + j * 16 + lr;
            int kc = dd >> 4, hi8 = (dd >> 3) & 1, e = dd & 7;
            float bia = bias[on + dd];
#pragma unroll
            for (int r = 0; r < 4; ++r) {
              int nl = i * 16 + lg * 4 + r;          // 0..63
              float val = acc[i][j][r] + bia;
              if (s == 0) val *= scale;
              FragS[(((nl >> 5) * 8 + kc) << 9) + ((hi8 * 32 + (nl & 31)) << 3) + e] = (bf16)val;
            }
          }
        }
      }
      __syncthreads();
      size_t base = ((size_t)bhh * 64 + (n0 >> 5) + pass * 2) * 4096;
#pragma unroll
      for (int r8 = 0; r8 < 4; ++r8) {
        bf16x8 v8 = *reinterpret_cast<const bf16x8*>(FragS + r8 * 2048 + tid * 8);
        *reinterpret_cast<bf16x8*>(dstbase + base + r8 * 2048 + tid * 8) = v8;
      }
    }
  } else {
    // v: transpose 128x128 tile through LDS, write fragment-major VF (16B stores)
    const int bb = tm >> 11, n0 = tm & 2047;
    const int bhh = bb * H_ + hblk;
    bf16(*Ts)[136] = reinterpret_cast<bf16(*)[136]>(As);
    for (int wc = 0; wc < 2; ++wc) {
#pragma unroll
      for (int j = 0; j < 4; ++j) {
        __syncthreads();
        if (wn == wc) {
          float bia = bias[on + wc * 64 + j * 16 + lr];
#pragma unroll
          for (int i = 0; i < 4; ++i) {
            bf16x4 pk;
#pragma unroll
            for (int r = 0; r < 4; ++r) pk[r] = (bf16)(acc[i][j][r] + bia);
            *reinterpret_cast<bf16x4*>(&Ts[lr][wm * 64 + i * 16 + lg * 4]) = pk;
          }
        }
        __syncthreads();
        int row = tid >> 4;
        int c8 = (tid & 15) * 8;
        bf16x8 v8 = *reinterpret_cast<const bf16x8*>(&Ts[row][c8]);
        int d = wc * 64 + j * 16 + row;
        int n = n0 + c8;
        size_t idx = (((((size_t)bhh * 32 + (n >> 6)) * 4 + ((n >> 4) & 3)) * 4 + (d >> 5)) << 9) +
                     ((((n >> 3) & 1) * 32 + (d & 31)) << 3);
        *reinterpret_cast<bf16x8*>(vt + idx) = v8;
      }
    }
  }
}

// ---------------- proj GEMM (bf16 MFMA): out = ab @ proj_w^T + b (fp32 out) ----------------
__global__ __launch_bounds__(256)
void proj_gemm(const bf16* __restrict__ A, const bf16* __restrict__ W,
               const float* __restrict__ bias, const float* __restrict__ mask6,
               float* __restrict__ out) {
  __shared__ bf16 As[128 * 32];
  __shared__ bf16 Bs[128 * 32];
  const int tid = threadIdx.x;
  const int l = tid & 63, w = tid >> 6;
  const int lr = l & 15, lg = l >> 4;
  const int wm = w >> 1, wn = w & 1;
  const int tm = blockIdx.y * 128;
  const int on = blockIdx.x * 128;

  f32x4 acc[4][4];
#pragma unroll
  for (int i = 0; i < 4; ++i)
#pragma unroll
    for (int j = 0; j < 4; ++j) acc[i][j] = f32x4{0.f, 0.f, 0.f, 0.f};

  for (int k0 = 0; k0 < DIM_; k0 += 32) {
    if (mask6[k0 >> 7] == 0.0f) continue;   // gated head's k-slice: A == 0 exactly
    __syncthreads();
#pragma unroll
    for (int u = 0; u < 2; ++u) {
      int row = w * 32 + u * 16 + (l >> 2);
      int cb = l & 3;
      gload16(A + (size_t)(tm + row) * DIM_ + k0 + cb * 8, As + (w * 32 + u * 16) * 32);
      gload16(W + (size_t)(on + row) * DIM_ + k0 + cb * 8, Bs + (w * 32 + u * 16) * 32);
    }
    __syncthreads();
    bf16x8 af[4], bfr[4];
#pragma unroll
    for (int i = 0; i < 4; ++i)
      af[i] = *reinterpret_cast<const bf16x8*>(As + (wm * 64 + i * 16 + lr) * 32 + lg * 8);
#pragma unroll
    for (int j = 0; j < 4; ++j)
      bfr[j] = *reinterpret_cast<const bf16x8*>(Bs + (wn * 64 + j * 16 + lr) * 32 + lg * 8);
#pragma unroll
    for (int i = 0; i < 4; ++i)
#pragma unroll
      for (int j = 0; j < 4; ++j)
        acc[i][j] = __builtin_amdgcn_mfma_f32_16x16x32_bf16(af[i], bfr[j], acc[i][j], 0, 0, 0);
  }

#pragma unroll
  for (int i = 0; i < 4; ++i) {
#pragma unroll
    for (int j = 0; j < 4; ++j) {
      int o = on + wn * 64 + j * 16 + lr;
      float bia = bias[o];
#pragma unroll
      for (int r = 0; r < 4; ++r) {
        int t = tm + wm * 64 + i * 16 + lg * 4 + r;
        out[(size_t)t * DIM_ + o] = acc[i][j][r] + bia;
      }
    }
  }
}

// ---------------- flash attention: 8-wave shared K/V ring, counted vmcnt ----------------
// 192 blocks (24 bh x 8 q-groups) x 512 threads. Each wave owns 32 q-rows; all 8
// waves share each 32-key fragment-major K/V tile, staged ONCE into a 3-deep LDS
// ring (2 gload16 per wave per tile). Per tile: vmcnt(2) + raw s_barrier (tile t
// staged; t+1's loads stay in flight). L2 traffic 8x lower than split-K (192 MB).
__global__ __launch_bounds__(512)
void attn_kernel(const bf16* __restrict__ qf_g, const bf16* __restrict__ kf_g,
                 const bf16* __restrict__ vf_g, const float* __restrict__ mask6,
                 bf16* __restrict__ ab) {
  __shared__ bf16 KS[3][4096];   // 8KB per ring slot
  __shared__ bf16 VS[3][4096];

  const int tid = threadIdx.x;
  const int l = tid & 63;
  const int w = tid >> 6;        // wave 0..7, owns q-rows qg*256 + w*32 ..+31
  const int kl = l & 31, hi = l >> 5;
  const int bid = blockIdx.x;
  const int bh = bid % 24;       // head-batch; bid%8 XCD classes keep K/V L2-local
  const int qg = bid / 24;       // 0..7
  const int h = bh % H_;
  const int b = bh / H_;
  const int q0 = qg * 256 + w * 32;
  const int loff = l * 8;
  const float hm = mask6[h];

  if (hm == 0.0f) {
    // gated head: 256 rows x 128 cols of exact zeros (uniform, before any barrier)
    bf16x8 z = __builtin_bit_cast(bf16x8, u32x4{0u, 0u, 0u, 0u});
    int row = tid >> 1, c0 = (tid & 1) * 64;
    bf16* dst = ab + ((size_t)b * SEQ_ + qg * 256 + row) * DIM_ + h * HD_ + c0;
#pragma unroll
    for (int u = 0; u < 8; ++u)
      *reinterpret_cast<bf16x8*>(dst + u * 8) = z;
    return;
  }

  const bf16* qq = qf_g + (((size_t)bh * 64 + qg * 8 + w) * 8) * 512;
  const bf16* kq = kf_g + (size_t)bh * 262144;
  const bf16* vq = vf_g + (size_t)bh * 262144;

  // Q fragments (coalesced, held all kernel)
  bf16x8 qf[8];
#pragma unroll
  for (int kc = 0; kc < 8; ++kc)
    qf[kc] = *reinterpret_cast<const bf16x8*>(qq + kc * 512 + loff);

  f32x16 oacc[4];
#pragma unroll
  for (int df = 0; df < 4; ++df)
#pragma unroll
    for (int r = 0; r < 16; ++r) oacc[df][r] = 0.f;
  float m_lane = -3.0e38f;   // running max for q-row = kl (log2 units)
  float lsum = 0.f;          // per-half-wave partial row sum

  // wave w stages fragment-column w of K and V (1KB each)
  auto STAGE = [&](int jj, int buf) {
    gload16(kq + (size_t)jj * 4096 + w * 512 + loff, &KS[buf][w * 512]);
    gload16(vq + (size_t)jj * 4096 + w * 512 + loff, &VS[buf][w * 512]);
  };

  STAGE(0, 0);
  STAGE(1, 1);

  for (int jj = 0; jj < 64; ++jj) {
    const int buf = jj % 3;
    // own tile-jj loads retired once <=2 newest (tile jj+1's pair) remain;
    // barrier publishes all waves' shares. Last tiles drain fully.
    if (jj < 62) asm volatile("s_waitcnt vmcnt(2)" ::: "memory");
    else         asm volatile("s_waitcnt vmcnt(0)" ::: "memory");
    __builtin_amdgcn_s_barrier();
    if (jj + 2 < 64) STAGE(jj + 2, (jj + 2) % 3);

    const bf16* Kc = &KS[buf][0];
    const bf16* Vc = &VS[buf][0];

    // S^T = K Q^T : lane (q=kl, hi) holds S[key][q]
    f32x16 sacc;
#pragma unroll
    for (int r = 0; r < 16; ++r) sacc[r] = 0.f;
    __builtin_amdgcn_s_setprio(1);
#pragma unroll
    for (int kc = 0; kc < 8; ++kc) {
      bf16x8 kfr = *reinterpret_cast<const bf16x8*>(Kc + kc * 512 + loff);
      sacc = __builtin_amdgcn_mfma_f32_32x32x16_bf16(kfr, qf[kc], sacc, 0, 0, 0);
    }
    __builtin_amdgcn_s_setprio(0);

    // lane-local online softmax for q-row = kl
    float t = sacc[0];
#pragma unroll
    for (int r = 1; r < 16; ++r) t = fmaxf(t, sacc[r]);
    t = fmaxf(t, __shfl_xor(t, 32));
    bool need = t > m_lane + 8.0f;  // defer-max (P bounded by 2^8)
    if (__ballot(need) != 0ull) {
      float nm = fmaxf(m_lane, t);
      float c = exp2f(m_lane - nm);
      m_lane = nm;
      lsum *= c;
#pragma unroll
      for (int r = 0; r < 16; ++r) {
        float cr = __shfl(c, (r & 3) + 8 * (r >> 2) + 4 * hi);
#pragma unroll
        for (int df = 0; df < 4; ++df) oacc[df][r] *= cr;
      }
    }

    // P = exp2(S - m) -> bf16 pairs
    u32 pp[8];
#pragma unroll
    for (int m = 0; m < 8; ++m) {
      float e0 = exp2f(sacc[2 * m] - m_lane);
      float e1 = exp2f(sacc[2 * m + 1] - m_lane);
      lsum += e0 + e1;
      union { u32 u; bf16 hh2[2]; } pk;
      pk.hh2[0] = (bf16)e0; pk.hh2[1] = (bf16)e1;
      pp[m] = pk.u;
    }

    // A-fragments for PV via permlane32_swap
    u32x4 afv[2];
#pragma unroll
    for (int ks = 0; ks < 2; ++ks) {
#pragma unroll
      for (int i = 0; i < 2; ++i) {
        u32 a = pp[4 * ks + i];
        u32 b2 = pp[4 * ks + 2 + i];
        asm volatile("v_permlane32_swap_b32 %0, %1" : "+v"(a), "+v"(b2));
        afv[ks][i] = a;
        afv[ks][2 + i] = b2;
      }
    }

    // PV: oacc[q][d] += P[q][key] V[key][d]
    __builtin_amdgcn_s_setprio(1);
#pragma unroll
    for (int ks = 0; ks < 2; ++ks) {
      bf16x8 pa = __builtin_bit_cast(bf16x8, afv[ks]);
#pragma unroll
      for (int df = 0; df < 4; ++df) {
        bf16x8 vfr = *reinterpret_cast<const bf16x8*>(Vc + (ks * 4 + df) * 512 + loff);
        oacc[df] = __builtin_amdgcn_mfma_f32_32x32x16_bf16(pa, vfr, oacc[df], 0, 0, 0);
      }
    }
    __builtin_amdgcn_s_setprio(0);
  }

  // epilogue: merge half-wave sums, normalize, head mask, write bf16 [t][c]
  float lt = lsum + __shfl_xor(lsum, 32);
  float inv_l = hm / lt;           // valid for q-row = kl at this lane
#pragma unroll
  for (int r = 0; r < 16; ++r) {
    int qloc = (r & 3) + 8 * (r >> 2) + 4 * hi;
    float invr = __shfl(inv_l, qloc);
    int n = q0 + qloc;
#pragma unroll
    for (int df = 0; df < 4; ++df) {
      int d = df * 32 + kl;
      ab[((size_t)b * SEQ_ + n) * DIM_ + h * HD_ + d] = (bf16)(oacc[df][r] * invr);
    }
  }
}

extern "C" void kernel_launch(void* const* d_in, const int* in_sizes, int n_in,
                              void* d_out, int out_size, void* d_ws, size_t ws_size,
                              hipStream_t stream) {
  const float* x        = (const float*)d_in[0];
  const float* latency  = (const float*)d_in[1];
  const float* qkv_w    = (const float*)d_in[2];
  const float* qkv_b    = (const float*)d_in[3];
  const float* proj_w   = (const float*)d_in[4];
  const float* proj_b   = (const float*)d_in[5];
  const float* router_w = (const float*)d_in[6];
  const float* router_b = (const float*)d_in[7];
  const float* g1       = (const float*)d_in[8];
  const float* g2       = (const float*)d_in[9];
  float* out = (float*)d_out;

  const size_t N_X  = (size_t)TOK_ * DIM_;
  const size_t N_WQ = (size_t)OUT3_ * DIM_;
  const size_t N_WP = (size_t)DIM_ * DIM_;
  const size_t N_P  = (size_t)NB_ * H_ * SEQ_ * HD_;

  float* maskp = (float*)d_ws;
  bf16* xb  = (bf16*)((char*)d_ws + 256);
  bf16* wqb = xb + N_X;
  bf16* wpb = wqb + N_WQ;
  bf16* qbf = wpb + N_WP;
  bf16* kbf = qbf + N_P;
  bf16* vtb = kbf + N_P;
  bf16* abf = vtb + N_P;

  size_t need = 256 + 2 * (N_X + N_WQ + N_WP + 4 * N_P);
  if (ws_size < need) return;

  mask_kernel<<<1, 64, 0, stream>>>(latency, router_w, router_b, g1, g2, maskp);
  convert_kernel<<<(int)(N_X / 1024), 256, 0, stream>>>(x, xb, (int)N_X);
  convert_kernel<<<(int)(N_WQ / 1024), 256, 0, stream>>>(qkv_w, wqb, (int)N_WQ);
  convert_kernel<<<(int)(N_WP / 1024), 256, 0, stream>>>(proj_w, wpb, (int)N_WP);

  qkv_gemm<<<dim3(OUT3_ / 128, TOK_ / 128), 256, 0, stream>>>(xb, wqb, qkv_b, maskp, qbf, kbf, vtb);
  attn_kernel<<<dim3(24 * 8), 512, 0, stream>>>(qbf, kbf, vtb, maskp, abf);
  proj_gemm<<<dim3(DIM_ / 128, TOK_ / 128), 256, 0, stream>>>(abf, wpb, proj_b, maskp, out);
}

// Round 17
// 187.291 us; speedup vs baseline: 1.0777x; 1.0777x over previous
//
#include <hip/hip_runtime.h>
#include <cstdint>

#define DIM_ 768
#define H_ 6
#define HD_ 128
#define NB_ 4
#define SEQ_ 2048
#define TOK_ (NB_*SEQ_)
#define OUT3_ (3*DIM_)
#define L2E 1.4426950408889634f

typedef __bf16 bf16;
typedef __bf16 bf16x4 __attribute__((ext_vector_type(4)));
typedef __bf16 bf16x8 __attribute__((ext_vector_type(8)));
typedef float f32x4 __attribute__((ext_vector_type(4)));
typedef float f32x16 __attribute__((ext_vector_type(16)));
typedef unsigned int u32;
typedef u32 u32x4 __attribute__((ext_vector_type(4)));

__device__ __forceinline__ void gload16(const void* g, void* lds) {
  __builtin_amdgcn_global_load_lds((const __attribute__((address_space(1))) void*)g,
                                   (__attribute__((address_space(3))) void*)lds,
                                   16, 0, 0);
}

// ---------------- fp32 -> bf16 convert ----------------
__global__ void convert_kernel(const float* __restrict__ in, bf16* __restrict__ out, int n) {
  int i = (blockIdx.x * 256 + threadIdx.x) * 4;
  if (i >= n) return;
  float4 v = *reinterpret_cast<const float4*>(in + i);
  bf16x4 o = { (bf16)v.x, (bf16)v.y, (bf16)v.z, (bf16)v.w };
  *reinterpret_cast<bf16x4*>(out + i) = o;
}

// ---------------- mask kernel ----------------
__global__ void mask_kernel(const float* __restrict__ latency,
                            const float* __restrict__ rw,
                            const float* __restrict__ rb,
                            const float* __restrict__ g1,
                            const float* __restrict__ g2,
                            float* __restrict__ mask6) {
  int i = threadIdx.x;
  if (i < 6) {
    int j = (i < 4) ? 0 : (i - 3);
    float logit = rw[j] * latency[0] + rb[j];
    float z = (logit + g1[j] - g2[j]) / 5.0f;
    float ys = 1.0f / (1.0f + expf(-z));
    float yh = ys > 0.5f ? 1.0f : 0.0f;
    mask6[i] = (yh - ys) + ys;   // exactly 0.0f when gated off
  }
}

// Fragment-major layouts (elements):
//  QF idx = (((bh*64 + n/32)*8 + kc)*512) + ((d>>3&1)*32 + n%32)*8 + d%8   [kc=d>>4]
//  KF identical formula to QF (verified: (bh*32+n/64)*2+(n>>5&1) == bh*64+n/32)
//  VF idx = ((((bh*32 + n/64)*4 + (n>>4&3))*4 + d/32)*512) + ((n>>3&1)*32 + d%32)*8 + n%8

// ---------------- QKV GEMM (bf16 MFMA): qkv = x @ qkv_w^T + b ----------------
// Single 48KB LDS arena; q/k epilogue = single-pass fragment staging (1 barrier),
// v epilogue = 2-half transpose (4 barriers). Gated heads exit immediately.
__global__ __launch_bounds__(256)
void qkv_gemm(const bf16* __restrict__ A, const bf16* __restrict__ W,
              const float* __restrict__ bias, const float* __restrict__ mask6,
              bf16* __restrict__ q, bf16* __restrict__ k, bf16* __restrict__ vt) {
  __shared__ bf16 SM[24576];     // 48KB: As[0..4095], Bs[4096..8191], Frag 32KB
  bf16* As = SM;
  bf16* Bs = SM + 4096;
  bf16* Frag = SM + 8192;        // 16384 elems
  const int tid = threadIdx.x;
  const int l = tid & 63, w = tid >> 6;
  const int lr = l & 15, lg = l >> 4;
  const int wm = w >> 1, wn = w & 1;
  const int tm = blockIdx.y * 128;
  const int on = blockIdx.x * 128;

  // head gating: block-uniform early exit
  const int sblk = (on < DIM_) ? 0 : (on < 2 * DIM_ ? 1 : 2);
  const int hblk = (on - sblk * DIM_) >> 7;
  if (mask6[hblk] == 0.0f) return;

  f32x4 acc[4][4];
#pragma unroll
  for (int i = 0; i < 4; ++i)
#pragma unroll
    for (int j = 0; j < 4; ++j) acc[i][j] = f32x4{0.f, 0.f, 0.f, 0.f};

  for (int k0 = 0; k0 < DIM_; k0 += 32) {
    __syncthreads();
#pragma unroll
    for (int u = 0; u < 2; ++u) {
      int row = w * 32 + u * 16 + (l >> 2);
      int cb = l & 3;
      gload16(A + (size_t)(tm + row) * DIM_ + k0 + cb * 8, As + (w * 32 + u * 16) * 32);
      gload16(W + (size_t)(on + row) * DIM_ + k0 + cb * 8, Bs + (w * 32 + u * 16) * 32);
    }
    __syncthreads();
    bf16x8 af[4], bfr[4];
#pragma unroll
    for (int i = 0; i < 4; ++i)
      af[i] = *reinterpret_cast<const bf16x8*>(As + (wm * 64 + i * 16 + lr) * 32 + lg * 8);
#pragma unroll
    for (int j = 0; j < 4; ++j)
      bfr[j] = *reinterpret_cast<const bf16x8*>(Bs + (wn * 64 + j * 16 + lr) * 32 + lg * 8);
#pragma unroll
    for (int i = 0; i < 4; ++i)
#pragma unroll
      for (int j = 0; j < 4; ++j)
        acc[i][j] = __builtin_amdgcn_mfma_f32_16x16x32_bf16(af[i], bfr[j], acc[i][j], 0, 0, 0);
  }

  const int n0 = tm & 2047;
  const int bb = tm >> 11;
  const int bhh = bb * H_ + hblk;

  if (on < 2 * DIM_) {
    // q/k: single-pass fragment-major staging of the full 128-row tile
    const int s = sblk;
    const float scale = 0.08838834764831845f * L2E;
    bf16* dstbase = (s == 0) ? q : k;
#pragma unroll
    for (int i = 0; i < 4; ++i) {
#pragma unroll
      for (int j = 0; j < 4; ++j) {
        int dd = wn * 64 + j * 16 + lr;
        int kc = dd >> 4, hi8 = (dd >> 3) & 1, e = dd & 7;
        float bia = bias[on + dd];
#pragma unroll
        for (int r = 0; r < 4; ++r) {
          int nl = wm * 64 + i * 16 + lg * 4 + r;    // 0..127
          float val = acc[i][j][r] + bia;
          if (s == 0) val *= scale;
          Frag[(((nl >> 5) * 8 + kc) << 9) + ((hi8 * 32 + (nl & 31)) << 3) + e] = (bf16)val;
        }
      }
    }
    __syncthreads();
    size_t base = ((size_t)bhh * 64 + (n0 >> 5)) * 4096;
#pragma unroll
    for (int it = 0; it < 8; ++it) {
      int idx = it * 2048 + tid * 8;
      bf16x8 v8 = *reinterpret_cast<const bf16x8*>(Frag + idx);
      *reinterpret_cast<bf16x8*>(dstbase + base + idx) = v8;
    }
  } else {
    // v: transpose through LDS in 2 halves of 64 d-cols, write fragment-major VF
    bf16(*Ts)[136] = reinterpret_cast<bf16(*)[136]>(Frag);  // 64 x 136
    for (int wc = 0; wc < 2; ++wc) {
      __syncthreads();
      if (wn == wc) {
#pragma unroll
        for (int j = 0; j < 4; ++j) {
          float bia = bias[on + wc * 64 + j * 16 + lr];
#pragma unroll
          for (int i = 0; i < 4; ++i) {
            bf16x4 pk;
#pragma unroll
            for (int r = 0; r < 4; ++r) pk[r] = (bf16)(acc[i][j][r] + bia);
            *reinterpret_cast<bf16x4*>(&Ts[j * 16 + lr][wm * 64 + i * 16 + lg * 4]) = pk;
          }
        }
      }
      __syncthreads();
#pragma unroll
      for (int it = 0; it < 4; ++it) {
        int row = it * 16 + (tid >> 4);    // d-local 0..63
        int c8 = (tid & 15) * 8;           // n-local
        bf16x8 v8 = *reinterpret_cast<const bf16x8*>(&Ts[row][c8]);
        int d = wc * 64 + row;
        int n = n0 + c8;
        size_t idx = (((((size_t)bhh * 32 + (n >> 6)) * 4 + ((n >> 4) & 3)) * 4 + (d >> 5)) << 9) +
                     ((((n >> 3) & 1) * 32 + (d & 31)) << 3);
        *reinterpret_cast<bf16x8*>(vt + idx) = v8;
      }
    }
  }
}

// ---------------- proj GEMM (bf16 MFMA): out = ab @ proj_w^T + b (fp32 out) ----------------
__global__ __launch_bounds__(256)
void proj_gemm(const bf16* __restrict__ A, const bf16* __restrict__ W,
               const float* __restrict__ bias, const float* __restrict__ mask6,
               float* __restrict__ out) {
  __shared__ bf16 As[128 * 32];
  __shared__ bf16 Bs[128 * 32];
  const int tid = threadIdx.x;
  const int l = tid & 63, w = tid >> 6;
  const int lr = l & 15, lg = l >> 4;
  const int wm = w >> 1, wn = w & 1;
  const int tm = blockIdx.y * 128;
  const int on = blockIdx.x * 128;

  f32x4 acc[4][4];
#pragma unroll
  for (int i = 0; i < 4; ++i)
#pragma unroll
    for (int j = 0; j < 4; ++j) acc[i][j] = f32x4{0.f, 0.f, 0.f, 0.f};

  for (int k0 = 0; k0 < DIM_; k0 += 32) {
    if (mask6[k0 >> 7] == 0.0f) continue;   // gated head's k-slice: A == 0 exactly
    __syncthreads();
#pragma unroll
    for (int u = 0; u < 2; ++u) {
      int row = w * 32 + u * 16 + (l >> 2);
      int cb = l & 3;
      gload16(A + (size_t)(tm + row) * DIM_ + k0 + cb * 8, As + (w * 32 + u * 16) * 32);
      gload16(W + (size_t)(on + row) * DIM_ + k0 + cb * 8, Bs + (w * 32 + u * 16) * 32);
    }
    __syncthreads();
    bf16x8 af[4], bfr[4];
#pragma unroll
    for (int i = 0; i < 4; ++i)
      af[i] = *reinterpret_cast<const bf16x8*>(As + (wm * 64 + i * 16 + lr) * 32 + lg * 8);
#pragma unroll
    for (int j = 0; j < 4; ++j)
      bfr[j] = *reinterpret_cast<const bf16x8*>(Bs + (wn * 64 + j * 16 + lr) * 32 + lg * 8);
#pragma unroll
    for (int i = 0; i < 4; ++i)
#pragma unroll
      for (int j = 0; j < 4; ++j)
        acc[i][j] = __builtin_amdgcn_mfma_f32_16x16x32_bf16(af[i], bfr[j], acc[i][j], 0, 0, 0);
  }

#pragma unroll
  for (int i = 0; i < 4; ++i) {
#pragma unroll
    for (int j = 0; j < 4; ++j) {
      int o = on + wn * 64 + j * 16 + lr;
      float bia = bias[o];
#pragma unroll
      for (int r = 0; r < 4; ++r) {
        int t = tm + wm * 64 + i * 16 + lg * 4 + r;
        out[(size_t)t * DIM_ + o] = acc[i][j][r] + bia;
      }
    }
  }
}

// ---------------- flash attention: barrier-free split-K, 32x32x16 MFMA ----------------
// (r11 structure — best measured: 97 us, VGPR 80, occ 26%)
__global__ __launch_bounds__(128, 2)
void attn_kernel(const bf16* __restrict__ qf_g, const bf16* __restrict__ kf_g,
                 const bf16* __restrict__ vf_g, const float* __restrict__ mask6,
                 bf16* __restrict__ ab) {
  __shared__ char smem[16640];   // [O1 16KB][m1 128B][l1 128B]

  const int tid = threadIdx.x;
  const int l = tid & 63;
  const int w = tid >> 6;        // key-half
  const int kl = l & 31, hi = l >> 5;
  const int bid = blockIdx.x;
  const int bh = bid % 24;       // all q-tiles of a head on one XCD class
  const int qt = bid / 24;       // 0..63
  const int h = bh % H_;
  const int b = bh / H_;
  const int q0 = qt * 32;
  const int loff = l * 8;
  const float hm = mask6[h];

  if (hm == 0.0f) {
    bf16x8 z = __builtin_bit_cast(bf16x8, u32x4{0u, 0u, 0u, 0u});
    int row = tid >> 2, c0 = (tid & 3) * 32;
    bf16* dst = ab + ((size_t)b * SEQ_ + q0 + row) * DIM_ + h * HD_ + c0;
#pragma unroll
    for (int u = 0; u < 4; ++u)
      *reinterpret_cast<bf16x8*>(dst + u * 8) = z;
    return;
  }

  float* OM  = (float*)smem;           // [32 q][128 d]
  float* MLm = (float*)(smem + 16384);
  float* MLl = MLm + 32;

  const bf16* qq = qf_g + (((size_t)bh * 64 + qt) * 8) * 512;
  const bf16* kq = kf_g + (size_t)bh * 262144 + (size_t)w * 32 * 4096;
  const bf16* vq = vf_g + (size_t)bh * 262144 + (size_t)w * 32 * 4096;

  bf16x8 qf[8];
#pragma unroll
  for (int kc = 0; kc < 8; ++kc)
    qf[kc] = *reinterpret_cast<const bf16x8*>(qq + kc * 512 + loff);

  f32x16 oacc[4];
#pragma unroll
  for (int df = 0; df < 4; ++df)
#pragma unroll
    for (int r = 0; r < 16; ++r) oacc[df][r] = 0.f;
  float m_lane = -3.0e38f;
  float lsum = 0.f;

  for (int jj = 0; jj < 32; ++jj) {
    const bf16* kb = kq + (size_t)jj * 4096;
    const bf16* vb = vq + (size_t)jj * 4096;

    f32x16 sacc;
#pragma unroll
    for (int r = 0; r < 16; ++r) sacc[r] = 0.f;
    __builtin_amdgcn_s_setprio(1);
#pragma unroll
    for (int kc = 0; kc < 8; ++kc) {
      bf16x8 kfr = *reinterpret_cast<const bf16x8*>(kb + kc * 512 + loff);
      sacc = __builtin_amdgcn_mfma_f32_32x32x16_bf16(kfr, qf[kc], sacc, 0, 0, 0);
    }
    __builtin_amdgcn_s_setprio(0);

    float t = sacc[0];
#pragma unroll
    for (int r = 1; r < 16; ++r) t = fmaxf(t, sacc[r]);
    t = fmaxf(t, __shfl_xor(t, 32));
    bool need = t > m_lane + 8.0f;
    if (__ballot(need) != 0ull) {
      float nm = fmaxf(m_lane, t);
      float c = exp2f(m_lane - nm);
      m_lane = nm;
      lsum *= c;
#pragma unroll
      for (int r = 0; r < 16; ++r) {
        float cr = __shfl(c, (r & 3) + 8 * (r >> 2) + 4 * hi);
#pragma unroll
        for (int df = 0; df < 4; ++df) oacc[df][r] *= cr;
      }
    }

    u32 pp[8];
#pragma unroll
    for (int m = 0; m < 8; ++m) {
      float e0 = exp2f(sacc[2 * m] - m_lane);
      float e1 = exp2f(sacc[2 * m + 1] - m_lane);
      lsum += e0 + e1;
      union { u32 u; bf16 hh2[2]; } pk;
      pk.hh2[0] = (bf16)e0; pk.hh2[1] = (bf16)e1;
      pp[m] = pk.u;
    }

    u32x4 afv[2];
#pragma unroll
    for (int ks = 0; ks < 2; ++ks) {
#pragma unroll
      for (int i = 0; i < 2; ++i) {
        u32 a = pp[4 * ks + i];
        u32 b2 = pp[4 * ks + 2 + i];
        asm volatile("v_permlane32_swap_b32 %0, %1" : "+v"(a), "+v"(b2));
        afv[ks][i] = a;
        afv[ks][2 + i] = b2;
      }
    }

    __builtin_amdgcn_s_setprio(1);
#pragma unroll
    for (int ks = 0; ks < 2; ++ks) {
      bf16x8 pa = __builtin_bit_cast(bf16x8, afv[ks]);
#pragma unroll
      for (int df = 0; df < 4; ++df) {
        bf16x8 vfr = *reinterpret_cast<const bf16x8*>(vb + (ks * 4 + df) * 512 + loff);
        oacc[df] = __builtin_amdgcn_mfma_f32_32x32x16_bf16(pa, vfr, oacc[df], 0, 0, 0);
      }
    }
    __builtin_amdgcn_s_setprio(0);
  }

  float lt = lsum + __shfl_xor(lsum, 32);

  if (w == 1) {
#pragma unroll
    for (int r = 0; r < 16; ++r) {
      int qloc = (r & 3) + 8 * (r >> 2) + 4 * hi;
#pragma unroll
      for (int df = 0; df < 4; ++df)
        OM[qloc * 128 + df * 32 + kl] = oacc[df][r];
    }
    MLm[kl] = m_lane;
    MLl[kl] = lt;
  }
  __syncthreads();
  if (w == 1) return;

  float m1 = MLm[kl];
  float l1 = MLl[kl];
  float M = fmaxf(m_lane, m1);
  float a0 = exp2f(m_lane - M), a1 = exp2f(m1 - M);
  float L = lt * a0 + l1 * a1;
  float s0 = a0 * hm / L, s1 = a1 * hm / L;

#pragma unroll
  for (int r = 0; r < 16; ++r) {
    int qloc = (r & 3) + 8 * (r >> 2) + 4 * hi;
    float r0 = __shfl(s0, qloc);
    float r1 = __shfl(s1, qloc);
    int n = q0 + qloc;
#pragma unroll
    for (int df = 0; df < 4; ++df) {
      int d = df * 32 + kl;
      float o1 = OM[qloc * 128 + df * 32 + kl];
      ab[((size_t)b * SEQ_ + n) * DIM_ + h * HD_ + d] =
          (bf16)(oacc[df][r] * r0 + o1 * r1);
    }
  }
}

extern "C" void kernel_launch(void* const* d_in, const int* in_sizes, int n_in,
                              void* d_out, int out_size, void* d_ws, size_t ws_size,
                              hipStream_t stream) {
  const float* x        = (const float*)d_in[0];
  const float* latency  = (const float*)d_in[1];
  const float* qkv_w    = (const float*)d_in[2];
  const float* qkv_b    = (const float*)d_in[3];
  const float* proj_w   = (const float*)d_in[4];
  const float* proj_b   = (const float*)d_in[5];
  const float* router_w = (const float*)d_in[6];
  const float* router_b = (const float*)d_in[7];
  const float* g1       = (const float*)d_in[8];
  const float* g2       = (const float*)d_in[9];
  float* out = (float*)d_out;

  const size_t N_X  = (size_t)TOK_ * DIM_;
  const size_t N_WQ = (size_t)OUT3_ * DIM_;
  const size_t N_WP = (size_t)DIM_ * DIM_;
  const size_t N_P  = (size_t)NB_ * H_ * SEQ_ * HD_;

  float* maskp = (float*)d_ws;
  bf16* xb  = (bf16*)((char*)d_ws + 256);
  bf16* wqb = xb + N_X;
  bf16* wpb = wqb + N_WQ;
  bf16* qbf = wpb + N_WP;
  bf16* kbf = qbf + N_P;
  bf16* vtb = kbf + N_P;
  bf16* abf = vtb + N_P;

  size_t need = 256 + 2 * (N_X + N_WQ + N_WP + 4 * N_P);
  if (ws_size < need) return;

  mask_kernel<<<1, 64, 0, stream>>>(latency, router_w, router_b, g1, g2, maskp);
  convert_kernel<<<(int)(N_X / 1024), 256, 0, stream>>>(x, xb, (int)N_X);
  convert_kernel<<<(int)(N_WQ / 1024), 256, 0, stream>>>(qkv_w, wqb, (int)N_WQ);
  convert_kernel<<<(int)(N_WP / 1024), 256, 0, stream>>>(proj_w, wpb, (int)N_WP);

  qkv_gemm<<<dim3(OUT3_ / 128, TOK_ / 128), 256, 0, stream>>>(xb, wqb, qkv_b, maskp, qbf, kbf, vtb);
  attn_kernel<<<dim3(24 * (SEQ_ / 32)), 128, 0, stream>>>(qbf, kbf, vtb, maskp, abf);
  proj_gemm<<<dim3(DIM_ / 128, TOK_ / 128), 256, 0, stream>>>(abf, wpb, proj_b, maskp, out);
}

// Round 18
// 179.410 us; speedup vs baseline: 1.1251x; 1.0439x over previous
//
#include <hip/hip_runtime.h>
#include <cstdint>

#define DIM_ 768
#define H_ 6
#define HD_ 128
#define NB_ 4
#define SEQ_ 2048
#define TOK_ (NB_*SEQ_)
#define OUT3_ (3*DIM_)
#define L2E 1.4426950408889634f

typedef __bf16 bf16;
typedef __bf16 bf16x4 __attribute__((ext_vector_type(4)));
typedef __bf16 bf16x8 __attribute__((ext_vector_type(8)));
typedef float f32x4 __attribute__((ext_vector_type(4)));
typedef float f32x16 __attribute__((ext_vector_type(16)));
typedef unsigned int u32;
typedef u32 u32x4 __attribute__((ext_vector_type(4)));

__device__ __forceinline__ void gload16(const void* g, void* lds) {
  __builtin_amdgcn_global_load_lds((const __attribute__((address_space(1))) void*)g,
                                   (__attribute__((address_space(3))) void*)lds,
                                   16, 0, 0);
}

// ---------------- fp32 -> bf16 convert ----------------
__global__ void convert_kernel(const float* __restrict__ in, bf16* __restrict__ out, int n) {
  int i = (blockIdx.x * 256 + threadIdx.x) * 4;
  if (i >= n) return;
  float4 v = *reinterpret_cast<const float4*>(in + i);
  bf16x4 o = { (bf16)v.x, (bf16)v.y, (bf16)v.z, (bf16)v.w };
  *reinterpret_cast<bf16x4*>(out + i) = o;
}

// ---------------- mask kernel ----------------
__global__ void mask_kernel(const float* __restrict__ latency,
                            const float* __restrict__ rw,
                            const float* __restrict__ rb,
                            const float* __restrict__ g1,
                            const float* __restrict__ g2,
                            float* __restrict__ mask6) {
  int i = threadIdx.x;
  if (i < 6) {
    int j = (i < 4) ? 0 : (i - 3);
    float logit = rw[j] * latency[0] + rb[j];
    float z = (logit + g1[j] - g2[j]) / 5.0f;
    float ys = 1.0f / (1.0f + expf(-z));
    float yh = ys > 0.5f ? 1.0f : 0.0f;
    mask6[i] = (yh - ys) + ys;   // exactly 0.0f when gated off
  }
}

// Fragment-major layouts (elements):
//  QF idx = (((bh*64 + n/32)*8 + kc)*512) + ((d>>3&1)*32 + n%32)*8 + d%8   [kc=d>>4]
//  KF identical formula to QF
//  VF idx = ((((bh*32 + n/64)*4 + (n>>4&3))*4 + d/32)*512) + ((n>>3&1)*32 + d%32)*8 + n%8
// GEMM LDS tiles (BK=64): linear [row][64] with 16B-block XOR swizzle
//  LDS[row][blk ^ (row&7)] = global[row][blk];  blk = col/8  (rule-21 both-sides swizzle)

// ---------------- QKV GEMM (bf16 MFMA, BK=64): qkv = x @ qkv_w^T + b ----------------
__global__ __launch_bounds__(256)
void qkv_gemm(const bf16* __restrict__ A, const bf16* __restrict__ W,
              const float* __restrict__ bias, const float* __restrict__ mask6,
              bf16* __restrict__ q, bf16* __restrict__ k, bf16* __restrict__ vt) {
  __shared__ bf16 SM[16384];     // 32KB arena: As[0..8191] Bs[8192..16383]; epi reuses
  bf16* As = SM;
  bf16* Bs = SM + 8192;
  bf16* Frag = SM;
  const int tid = threadIdx.x;
  const int l = tid & 63, w = tid >> 6;
  const int lr = l & 15, lg = l >> 4;
  const int wm = w >> 1, wn = w & 1;
  const int tm = blockIdx.y * 128;
  const int on = blockIdx.x * 128;

  const int sblk = (on < DIM_) ? 0 : (on < 2 * DIM_ ? 1 : 2);
  const int hblk = (on - sblk * DIM_) >> 7;
  if (mask6[hblk] == 0.0f) return;

  const int lrow = l >> 3;                       // staging row-within-8
  const int scol = ((l & 7) ^ lrow) * 8;         // pre-swizzled source col

  f32x4 acc[4][4];
#pragma unroll
  for (int i = 0; i < 4; ++i)
#pragma unroll
    for (int j = 0; j < 4; ++j) acc[i][j] = f32x4{0.f, 0.f, 0.f, 0.f};

  for (int k0 = 0; k0 < DIM_; k0 += 64) {
    __syncthreads();
#pragma unroll
    for (int u = 0; u < 4; ++u) {
      int br = w * 32 + u * 8;
      gload16(A + (size_t)(tm + br + lrow) * DIM_ + k0 + scol, As + br * 64);
      gload16(W + (size_t)(on + br + lrow) * DIM_ + k0 + scol, Bs + br * 64);
    }
    __syncthreads();
#pragma unroll
    for (int kk = 0; kk < 2; ++kk) {
      bf16x8 af[4], bfr[4];
#pragma unroll
      for (int i = 0; i < 4; ++i) {
        int row = wm * 64 + i * 16 + lr;
        af[i] = *reinterpret_cast<const bf16x8*>(As + row * 64 + (((kk << 2) + lg) ^ (row & 7)) * 8);
      }
#pragma unroll
      for (int j = 0; j < 4; ++j) {
        int row = wn * 64 + j * 16 + lr;
        bfr[j] = *reinterpret_cast<const bf16x8*>(Bs + row * 64 + (((kk << 2) + lg) ^ (row & 7)) * 8);
      }
#pragma unroll
      for (int i = 0; i < 4; ++i)
#pragma unroll
        for (int j = 0; j < 4; ++j)
          acc[i][j] = __builtin_amdgcn_mfma_f32_16x16x32_bf16(af[i], bfr[j], acc[i][j], 0, 0, 0);
    }
  }

  const int n0 = tm & 2047;
  const int bb = tm >> 11;
  const int bhh = bb * H_ + hblk;

  if (on < 2 * DIM_) {
    // q/k: single-pass fragment-major staging of the full 128-row tile
    const int s = sblk;
    const float scale = 0.08838834764831845f * L2E;
    bf16* dstbase = (s == 0) ? q : k;
    __syncthreads();
#pragma unroll
    for (int i = 0; i < 4; ++i) {
#pragma unroll
      for (int j = 0; j < 4; ++j) {
        int dd = wn * 64 + j * 16 + lr;
        int kc = dd >> 4, hi8 = (dd >> 3) & 1, e = dd & 7;
        float bia = bias[on + dd];
#pragma unroll
        for (int r = 0; r < 4; ++r) {
          int nl = wm * 64 + i * 16 + lg * 4 + r;    // 0..127
          float val = acc[i][j][r] + bia;
          if (s == 0) val *= scale;
          Frag[(((nl >> 5) * 8 + kc) << 9) + ((hi8 * 32 + (nl & 31)) << 3) + e] = (bf16)val;
        }
      }
    }
    __syncthreads();
    size_t base = ((size_t)bhh * 64 + (n0 >> 5)) * 4096;
#pragma unroll
    for (int it = 0; it < 8; ++it) {
      int idx = it * 2048 + tid * 8;
      bf16x8 v8 = *reinterpret_cast<const bf16x8*>(Frag + idx);
      *reinterpret_cast<bf16x8*>(dstbase + base + idx) = v8;
    }
  } else {
    // v: transpose through LDS in 2 halves of 64 d-cols, write fragment-major VF
    bf16(*Ts)[136] = reinterpret_cast<bf16(*)[136]>(Frag);  // 64 x 136
    for (int wc = 0; wc < 2; ++wc) {
      __syncthreads();
      if (wn == wc) {
#pragma unroll
        for (int j = 0; j < 4; ++j) {
          float bia = bias[on + wc * 64 + j * 16 + lr];
#pragma unroll
          for (int i = 0; i < 4; ++i) {
            bf16x4 pk;
#pragma unroll
            for (int r = 0; r < 4; ++r) pk[r] = (bf16)(acc[i][j][r] + bia);
            *reinterpret_cast<bf16x4*>(&Ts[j * 16 + lr][wm * 64 + i * 16 + lg * 4]) = pk;
          }
        }
      }
      __syncthreads();
#pragma unroll
      for (int it = 0; it < 4; ++it) {
        int row = it * 16 + (tid >> 4);    // d-local 0..63
        int c8 = (tid & 15) * 8;           // n-local
        bf16x8 v8 = *reinterpret_cast<const bf16x8*>(&Ts[row][c8]);
        int d = wc * 64 + row;
        int n = n0 + c8;
        size_t idx = (((((size_t)bhh * 32 + (n >> 6)) * 4 + ((n >> 4) & 3)) * 4 + (d >> 5)) << 9) +
                     ((((n >> 3) & 1) * 32 + (d & 31)) << 3);
        *reinterpret_cast<bf16x8*>(vt + idx) = v8;
      }
    }
  }
}

// ---------------- proj GEMM (bf16 MFMA, 128x64 tile, BK=64) ----------------
// grid (768/64, 8192/128) = (12, 64) = 768 blocks = 3/CU.
__global__ __launch_bounds__(256)
void proj_gemm(const bf16* __restrict__ A, const bf16* __restrict__ W,
               const float* __restrict__ bias, const float* __restrict__ mask6,
               float* __restrict__ out) {
  __shared__ bf16 As[128 * 64];   // 16KB
  __shared__ bf16 Bs[64 * 64];    // 8KB
  const int tid = threadIdx.x;
  const int l = tid & 63, w = tid >> 6;
  const int lr = l & 15, lg = l >> 4;
  const int wm = w >> 1, wn = w & 1;
  const int tm = blockIdx.y * 128;
  const int on = blockIdx.x * 64;

  const int lrow = l >> 3;
  const int scol = ((l & 7) ^ lrow) * 8;

  f32x4 acc[4][2];
#pragma unroll
  for (int i = 0; i < 4; ++i)
#pragma unroll
    for (int j = 0; j < 2; ++j) acc[i][j] = f32x4{0.f, 0.f, 0.f, 0.f};

  for (int k0 = 0; k0 < DIM_; k0 += 64) {
    if (mask6[k0 >> 7] == 0.0f) continue;   // gated head's k-slice: A == 0 exactly
    __syncthreads();
#pragma unroll
    for (int u = 0; u < 4; ++u) {
      int br = w * 32 + u * 8;
      gload16(A + (size_t)(tm + br + lrow) * DIM_ + k0 + scol, As + br * 64);
    }
#pragma unroll
    for (int u = 0; u < 2; ++u) {
      int br = w * 16 + u * 8;
      gload16(W + (size_t)(on + br + lrow) * DIM_ + k0 + scol, Bs + br * 64);
    }
    __syncthreads();
#pragma unroll
    for (int kk = 0; kk < 2; ++kk) {
      bf16x8 af[4], bfr[2];
#pragma unroll
      for (int i = 0; i < 4; ++i) {
        int row = wm * 64 + i * 16 + lr;
        af[i] = *reinterpret_cast<const bf16x8*>(As + row * 64 + (((kk << 2) + lg) ^ (row & 7)) * 8);
      }
#pragma unroll
      for (int j = 0; j < 2; ++j) {
        int row = wn * 32 + j * 16 + lr;
        bfr[j] = *reinterpret_cast<const bf16x8*>(Bs + row * 64 + (((kk << 2) + lg) ^ (row & 7)) * 8);
      }
#pragma unroll
      for (int i = 0; i < 4; ++i)
#pragma unroll
        for (int j = 0; j < 2; ++j)
          acc[i][j] = __builtin_amdgcn_mfma_f32_16x16x32_bf16(af[i], bfr[j], acc[i][j], 0, 0, 0);
    }
  }

#pragma unroll
  for (int i = 0; i < 4; ++i) {
#pragma unroll
    for (int j = 0; j < 2; ++j) {
      int o = on + wn * 32 + j * 16 + lr;
      float bia = bias[o];
#pragma unroll
      for (int r = 0; r < 4; ++r) {
        int t = tm + wm * 64 + i * 16 + lg * 4 + r;
        out[(size_t)t * DIM_ + o] = acc[i][j][r] + bia;
      }
    }
  }
}

// ---------------- flash attention: barrier-free split-K, 32x32x16 MFMA ----------------
// (r11 structure — best measured: 97 us, VGPR 80, occ 26%)
__global__ __launch_bounds__(128, 2)
void attn_kernel(const bf16* __restrict__ qf_g, const bf16* __restrict__ kf_g,
                 const bf16* __restrict__ vf_g, const float* __restrict__ mask6,
                 bf16* __restrict__ ab) {
  __shared__ char smem[16640];   // [O1 16KB][m1 128B][l1 128B]

  const int tid = threadIdx.x;
  const int l = tid & 63;
  const int w = tid >> 6;        // key-half
  const int kl = l & 31, hi = l >> 5;
  const int bid = blockIdx.x;
  const int bh = bid % 24;       // all q-tiles of a head on one XCD class
  const int qt = bid / 24;       // 0..63
  const int h = bh % H_;
  const int b = bh / H_;
  const int q0 = qt * 32;
  const int loff = l * 8;
  const float hm = mask6[h];

  if (hm == 0.0f) {
    bf16x8 z = __builtin_bit_cast(bf16x8, u32x4{0u, 0u, 0u, 0u});
    int row = tid >> 2, c0 = (tid & 3) * 32;
    bf16* dst = ab + ((size_t)b * SEQ_ + q0 + row) * DIM_ + h * HD_ + c0;
#pragma unroll
    for (int u = 0; u < 4; ++u)
      *reinterpret_cast<bf16x8*>(dst + u * 8) = z;
    return;
  }

  float* OM  = (float*)smem;           // [32 q][128 d]
  float* MLm = (float*)(smem + 16384);
  float* MLl = MLm + 32;

  const bf16* qq = qf_g + (((size_t)bh * 64 + qt) * 8) * 512;
  const bf16* kq = kf_g + (size_t)bh * 262144 + (size_t)w * 32 * 4096;
  const bf16* vq = vf_g + (size_t)bh * 262144 + (size_t)w * 32 * 4096;

  bf16x8 qf[8];
#pragma unroll
  for (int kc = 0; kc < 8; ++kc)
    qf[kc] = *reinterpret_cast<const bf16x8*>(qq + kc * 512 + loff);

  f32x16 oacc[4];
#pragma unroll
  for (int df = 0; df < 4; ++df)
#pragma unroll
    for (int r = 0; r < 16; ++r) oacc[df][r] = 0.f;
  float m_lane = -3.0e38f;
  float lsum = 0.f;

  for (int jj = 0; jj < 32; ++jj) {
    const bf16* kb = kq + (size_t)jj * 4096;
    const bf16* vb = vq + (size_t)jj * 4096;

    f32x16 sacc;
#pragma unroll
    for (int r = 0; r < 16; ++r) sacc[r] = 0.f;
    __builtin_amdgcn_s_setprio(1);
#pragma unroll
    for (int kc = 0; kc < 8; ++kc) {
      bf16x8 kfr = *reinterpret_cast<const bf16x8*>(kb + kc * 512 + loff);
      sacc = __builtin_amdgcn_mfma_f32_32x32x16_bf16(kfr, qf[kc], sacc, 0, 0, 0);
    }
    __builtin_amdgcn_s_setprio(0);

    float t = sacc[0];
#pragma unroll
    for (int r = 1; r < 16; ++r) t = fmaxf(t, sacc[r]);
    t = fmaxf(t, __shfl_xor(t, 32));
    bool need = t > m_lane + 8.0f;
    if (__ballot(need) != 0ull) {
      float nm = fmaxf(m_lane, t);
      float c = exp2f(m_lane - nm);
      m_lane = nm;
      lsum *= c;
#pragma unroll
      for (int r = 0; r < 16; ++r) {
        float cr = __shfl(c, (r & 3) + 8 * (r >> 2) + 4 * hi);
#pragma unroll
        for (int df = 0; df < 4; ++df) oacc[df][r] *= cr;
      }
    }

    u32 pp[8];
#pragma unroll
    for (int m = 0; m < 8; ++m) {
      float e0 = exp2f(sacc[2 * m] - m_lane);
      float e1 = exp2f(sacc[2 * m + 1] - m_lane);
      lsum += e0 + e1;
      union { u32 u; bf16 hh2[2]; } pk;
      pk.hh2[0] = (bf16)e0; pk.hh2[1] = (bf16)e1;
      pp[m] = pk.u;
    }

    u32x4 afv[2];
#pragma unroll
    for (int ks = 0; ks < 2; ++ks) {
#pragma unroll
      for (int i = 0; i < 2; ++i) {
        u32 a = pp[4 * ks + i];
        u32 b2 = pp[4 * ks + 2 + i];
        asm volatile("v_permlane32_swap_b32 %0, %1" : "+v"(a), "+v"(b2));
        afv[ks][i] = a;
        afv[ks][2 + i] = b2;
      }
    }

    __builtin_amdgcn_s_setprio(1);
#pragma unroll
    for (int ks = 0; ks < 2; ++ks) {
      bf16x8 pa = __builtin_bit_cast(bf16x8, afv[ks]);
#pragma unroll
      for (int df = 0; df < 4; ++df) {
        bf16x8 vfr = *reinterpret_cast<const bf16x8*>(vb + (ks * 4 + df) * 512 + loff);
        oacc[df] = __builtin_amdgcn_mfma_f32_32x32x16_bf16(pa, vfr, oacc[df], 0, 0, 0);
      }
    }
    __builtin_amdgcn_s_setprio(0);
  }

  float lt = lsum + __shfl_xor(lsum, 32);

  if (w == 1) {
#pragma unroll
    for (int r = 0; r < 16; ++r) {
      int qloc = (r & 3) + 8 * (r >> 2) + 4 * hi;
#pragma unroll
      for (int df = 0; df < 4; ++df)
        OM[qloc * 128 + df * 32 + kl] = oacc[df][r];
    }
    MLm[kl] = m_lane;
    MLl[kl] = lt;
  }
  __syncthreads();
  if (w == 1) return;

  float m1 = MLm[kl];
  float l1 = MLl[kl];
  float M = fmaxf(m_lane, m1);
  float a0 = exp2f(m_lane - M), a1 = exp2f(m1 - M);
  float L = lt * a0 + l1 * a1;
  float s0 = a0 * hm / L, s1 = a1 * hm / L;

#pragma unroll
  for (int r = 0; r < 16; ++r) {
    int qloc = (r & 3) + 8 * (r >> 2) + 4 * hi;
    float r0 = __shfl(s0, qloc);
    float r1 = __shfl(s1, qloc);
    int n = q0 + qloc;
#pragma unroll
    for (int df = 0; df < 4; ++df) {
      int d = df * 32 + kl;
      float o1 = OM[qloc * 128 + df * 32 + kl];
      ab[((size_t)b * SEQ_ + n) * DIM_ + h * HD_ + d] =
          (bf16)(oacc[df][r] * r0 + o1 * r1);
    }
  }
}

extern "C" void kernel_launch(void* const* d_in, const int* in_sizes, int n_in,
                              void* d_out, int out_size, void* d_ws, size_t ws_size,
                              hipStream_t stream) {
  const float* x        = (const float*)d_in[0];
  const float* latency  = (const float*)d_in[1];
  const float* qkv_w    = (const float*)d_in[2];
  const float* qkv_b    = (const float*)d_in[3];
  const float* proj_w   = (const float*)d_in[4];
  const float* proj_b   = (const float*)d_in[5];
  const float* router_w = (const float*)d_in[6];
  const float* router_b = (const float*)d_in[7];
  const float* g1       = (const float*)d_in[8];
  const float* g2       = (const float*)d_in[9];
  float* out = (float*)d_out;

  const size_t N_X  = (size_t)TOK_ * DIM_;
  const size_t N_WQ = (size_t)OUT3_ * DIM_;
  const size_t N_WP = (size_t)DIM_ * DIM_;
  const size_t N_P  = (size_t)NB_ * H_ * SEQ_ * HD_;

  float* maskp = (float*)d_ws;
  bf16* xb  = (bf16*)((char*)d_ws + 256);
  bf16* wqb = xb + N_X;
  bf16* wpb = wqb + N_WQ;
  bf16* qbf = wpb + N_WP;
  bf16* kbf = qbf + N_P;
  bf16* vtb = kbf + N_P;
  bf16* abf = vtb + N_P;

  size_t need = 256 + 2 * (N_X + N_WQ + N_WP + 4 * N_P);
  if (ws_size < need) return;

  mask_kernel<<<1, 64, 0, stream>>>(latency, router_w, router_b, g1, g2, maskp);
  convert_kernel<<<(int)(N_X / 1024), 256, 0, stream>>>(x, xb, (int)N_X);
  convert_kernel<<<(int)(N_WQ / 1024), 256, 0, stream>>>(qkv_w, wqb, (int)N_WQ);
  convert_kernel<<<(int)(N_WP / 1024), 256, 0, stream>>>(proj_w, wpb, (int)N_WP);

  qkv_gemm<<<dim3(OUT3_ / 128, TOK_ / 128), 256, 0, stream>>>(xb, wqb, qkv_b, maskp, qbf, kbf, vtb);
  attn_kernel<<<dim3(24 * (SEQ_ / 32)), 128, 0, stream>>>(qbf, kbf, vtb, maskp, abf);
  proj_gemm<<<dim3(DIM_ / 64, TOK_ / 128), 256, 0, stream>>>(abf, wpb, proj_b, maskp, out);
}

// Round 19
// 171.239 us; speedup vs baseline: 1.1788x; 1.0477x over previous
//
#include <hip/hip_runtime.h>
#include <cstdint>

#define DIM_ 768
#define H_ 6
#define HD_ 128
#define NB_ 4
#define SEQ_ 2048
#define TOK_ (NB_*SEQ_)
#define OUT3_ (3*DIM_)
#define L2E 1.4426950408889634f

typedef __bf16 bf16;
typedef __bf16 bf16x4 __attribute__((ext_vector_type(4)));
typedef __bf16 bf16x8 __attribute__((ext_vector_type(8)));
typedef float f32x4 __attribute__((ext_vector_type(4)));
typedef float f32x16 __attribute__((ext_vector_type(16)));
typedef unsigned int u32;
typedef u32 u32x4 __attribute__((ext_vector_type(4)));

__device__ __forceinline__ void gload16(const void* g, void* lds) {
  __builtin_amdgcn_global_load_lds((const __attribute__((address_space(1))) void*)g,
                                   (__attribute__((address_space(3))) void*)lds,
                                   16, 0, 0);
}

// ---------------- fused prep: fp32->bf16 converts (x, qkv_w, proj_w) + mask ----------------
__global__ void prep_kernel(const float* __restrict__ x, const float* __restrict__ qw,
                            const float* __restrict__ pw,
                            const float* __restrict__ latency, const float* __restrict__ rw,
                            const float* __restrict__ rb, const float* __restrict__ g1,
                            const float* __restrict__ g2,
                            bf16* __restrict__ xb, bf16* __restrict__ wqb,
                            bf16* __restrict__ wpb, float* __restrict__ mask6) {
  if (blockIdx.x == 0 && threadIdx.x < 6) {
    int i = threadIdx.x;
    int j = (i < 4) ? 0 : (i - 3);
    float logit = rw[j] * latency[0] + rb[j];
    float z = (logit + g1[j] - g2[j]) / 5.0f;
    float ys = 1.0f / (1.0f + expf(-z));
    float yh = ys > 0.5f ? 1.0f : 0.0f;
    mask6[i] = (yh - ys) + ys;   // exactly 0.0f when gated off
  }
  const int QX  = TOK_ * DIM_ / 4;      // 1572864 quads
  const int QWQ = OUT3_ * DIM_ / 4;     // 442368
  int gid = blockIdx.x * 256 + threadIdx.x;
  const float* src;
  bf16* dst;
  int off;
  if (gid < QX) { src = x; dst = xb; off = gid; }
  else if (gid < QX + QWQ) { src = qw; dst = wqb; off = gid - QX; }
  else { src = pw; dst = wpb; off = gid - QX - QWQ; }
  float4 v = *reinterpret_cast<const float4*>(src + off * 4);
  bf16x4 o = { (bf16)v.x, (bf16)v.y, (bf16)v.z, (bf16)v.w };
  *reinterpret_cast<bf16x4*>(dst + off * 4) = o;
}

// Fragment-major layouts (elements):
//  QF idx = (((bh*64 + n/32)*8 + kc)*512) + ((d>>3&1)*32 + n%32)*8 + d%8   [kc=d>>4]
//  KF identical formula to QF
//  VF idx = ((((bh*32 + n/64)*4 + (n>>4&3))*4 + d/32)*512) + ((n>>3&1)*32 + d%32)*8 + n%8
// GEMM LDS tiles: [row][BK] linear with 16B-block XOR swizzle (rule-21 both sides)

// ---------------- QKV GEMM (bf16 MFMA, BK=32 double-buffered, 1 barrier/step) -------
__global__ __launch_bounds__(256)
void qkv_gemm(const bf16* __restrict__ A, const bf16* __restrict__ W,
              const float* __restrict__ bias, const float* __restrict__ mask6,
              bf16* __restrict__ q, bf16* __restrict__ k, bf16* __restrict__ vt) {
  __shared__ bf16 AB[2][8192];   // per buf: As [0..4095], Bs [4096..8191] (16KB each)
  bf16* Frag = &AB[0][0];        // 32KB epilogue arena (reuses both bufs)
  const int tid = threadIdx.x;
  const int l = tid & 63, w = tid >> 6;
  const int lr = l & 15, lg = l >> 4;
  const int wm = w >> 1, wn = w & 1;
  const int tm = blockIdx.y * 128;
  const int on = blockIdx.x * 128;

  const int sblk = (on < DIM_) ? 0 : (on < 2 * DIM_ ? 1 : 2);
  const int hblk = (on - sblk * DIM_) >> 7;
  if (mask6[hblk] == 0.0f) return;

  const int lrow = l >> 2;                        // row-within-16 staged by this lane
  const int scol = ((l & 3) ^ (lrow & 3)) * 8;    // pre-swizzled source col

  f32x4 acc[4][4];
#pragma unroll
  for (int i = 0; i < 4; ++i)
#pragma unroll
    for (int j = 0; j < 4; ++j) acc[i][j] = f32x4{0.f, 0.f, 0.f, 0.f};

  auto STAGE = [&](int k0, int buf) {
#pragma unroll
    for (int u = 0; u < 2; ++u) {
      int rbase = w * 32 + u * 16;
      gload16(A + (size_t)(tm + rbase + lrow) * DIM_ + k0 + scol, &AB[buf][rbase * 32]);
      gload16(W + (size_t)(on + rbase + lrow) * DIM_ + k0 + scol, &AB[buf][4096 + rbase * 32]);
    }
  };

  STAGE(0, 0);
  __syncthreads();
  for (int t = 0; t < 24; ++t) {
    if (t + 1 < 24) STAGE((t + 1) * 32, (t + 1) & 1);
    const bf16* As = &AB[t & 1][0];
    const bf16* Bs = &AB[t & 1][4096];
    bf16x8 af[4], bfr[4];
#pragma unroll
    for (int i = 0; i < 4; ++i) {
      int row = wm * 64 + i * 16 + lr;
      af[i] = *reinterpret_cast<const bf16x8*>(As + row * 32 + ((lg ^ (row & 3)) * 8));
    }
#pragma unroll
    for (int j = 0; j < 4; ++j) {
      int row = wn * 64 + j * 16 + lr;
      bfr[j] = *reinterpret_cast<const bf16x8*>(Bs + row * 32 + ((lg ^ (row & 3)) * 8));
    }
#pragma unroll
    for (int i = 0; i < 4; ++i)
#pragma unroll
      for (int j = 0; j < 4; ++j)
        acc[i][j] = __builtin_amdgcn_mfma_f32_16x16x32_bf16(af[i], bfr[j], acc[i][j], 0, 0, 0);
    __syncthreads();
  }

  const int n0 = tm & 2047;
  const int bb = tm >> 11;
  const int bhh = bb * H_ + hblk;

  if (on < 2 * DIM_) {
    // q/k: single-pass fragment-major staging of the full 128-row tile
    const int s = sblk;
    const float scale = 0.08838834764831845f * L2E;
    bf16* dstbase = (s == 0) ? q : k;
#pragma unroll
    for (int i = 0; i < 4; ++i) {
#pragma unroll
      for (int j = 0; j < 4; ++j) {
        int dd = wn * 64 + j * 16 + lr;
        int kc = dd >> 4, hi8 = (dd >> 3) & 1, e = dd & 7;
        float bia = bias[on + dd];
#pragma unroll
        for (int r = 0; r < 4; ++r) {
          int nl = wm * 64 + i * 16 + lg * 4 + r;    // 0..127
          float val = acc[i][j][r] + bia;
          if (s == 0) val *= scale;
          Frag[(((nl >> 5) * 8 + kc) << 9) + ((hi8 * 32 + (nl & 31)) << 3) + e] = (bf16)val;
        }
      }
    }
    __syncthreads();
    size_t base = ((size_t)bhh * 64 + (n0 >> 5)) * 4096;
#pragma unroll
    for (int it = 0; it < 8; ++it) {
      int idx = it * 2048 + tid * 8;
      bf16x8 v8 = *reinterpret_cast<const bf16x8*>(Frag + idx);
      *reinterpret_cast<bf16x8*>(dstbase + base + idx) = v8;
    }
  } else {
    // v: transpose through LDS in 2 halves of 64 d-cols, write fragment-major VF
    bf16(*Ts)[136] = reinterpret_cast<bf16(*)[136]>(Frag);  // 64 x 136
    for (int wc = 0; wc < 2; ++wc) {
      __syncthreads();
      if (wn == wc) {
#pragma unroll
        for (int j = 0; j < 4; ++j) {
          float bia = bias[on + wc * 64 + j * 16 + lr];
#pragma unroll
          for (int i = 0; i < 4; ++i) {
            bf16x4 pk;
#pragma unroll
            for (int r = 0; r < 4; ++r) pk[r] = (bf16)(acc[i][j][r] + bia);
            *reinterpret_cast<bf16x4*>(&Ts[j * 16 + lr][wm * 64 + i * 16 + lg * 4]) = pk;
          }
        }
      }
      __syncthreads();
#pragma unroll
      for (int it = 0; it < 4; ++it) {
        int row = it * 16 + (tid >> 4);    // d-local 0..63
        int c8 = (tid & 15) * 8;           // n-local
        bf16x8 v8 = *reinterpret_cast<const bf16x8*>(&Ts[row][c8]);
        int d = wc * 64 + row;
        int n = n0 + c8;
        size_t idx = (((((size_t)bhh * 32 + (n >> 6)) * 4 + ((n >> 4) & 3)) * 4 + (d >> 5)) << 9) +
                     ((((n >> 3) & 1) * 32 + (d & 31)) << 3);
        *reinterpret_cast<bf16x8*>(vt + idx) = v8;
      }
    }
  }
}

// ---------------- proj GEMM (bf16 MFMA, 128x64 tile, BK=64, double-buffered) --------
// grid (12, 64) = 768 blocks = 3/CU; LDS 48KB = 3 blocks/CU exactly.
__global__ __launch_bounds__(256)
void proj_gemm(const bf16* __restrict__ A, const bf16* __restrict__ W,
               const float* __restrict__ bias, float* __restrict__ out) {
  __shared__ bf16 AB[2][12288];  // per buf: As 128x64 [0..8191], Bs 64x64 [8192..12287]
  const int tid = threadIdx.x;
  const int l = tid & 63, w = tid >> 6;
  const int lr = l & 15, lg = l >> 4;
  const int wm = w >> 1, wn = w & 1;
  const int tm = blockIdx.y * 128;
  const int on = blockIdx.x * 64;

  const int lrow = l >> 3;
  const int scol = ((l & 7) ^ lrow) * 8;

  f32x4 acc[4][2];
#pragma unroll
  for (int i = 0; i < 4; ++i)
#pragma unroll
    for (int j = 0; j < 2; ++j) acc[i][j] = f32x4{0.f, 0.f, 0.f, 0.f};

  auto STAGE = [&](int k0, int buf) {
#pragma unroll
    for (int u = 0; u < 4; ++u) {
      int br = w * 32 + u * 8;
      gload16(A + (size_t)(tm + br + lrow) * DIM_ + k0 + scol, &AB[buf][br * 64]);
    }
#pragma unroll
    for (int u = 0; u < 2; ++u) {
      int br = w * 16 + u * 8;
      gload16(W + (size_t)(on + br + lrow) * DIM_ + k0 + scol, &AB[buf][8192 + br * 64]);
    }
  };

  STAGE(0, 0);
  __syncthreads();
  for (int t = 0; t < 12; ++t) {
    if (t + 1 < 12) STAGE((t + 1) * 64, (t + 1) & 1);
    const bf16* As = &AB[t & 1][0];
    const bf16* Bs = &AB[t & 1][8192];
#pragma unroll
    for (int kk = 0; kk < 2; ++kk) {
      bf16x8 af[4], bfr[2];
#pragma unroll
      for (int i = 0; i < 4; ++i) {
        int row = wm * 64 + i * 16 + lr;
        af[i] = *reinterpret_cast<const bf16x8*>(As + row * 64 + (((kk << 2) + lg) ^ (row & 7)) * 8);
      }
#pragma unroll
      for (int j = 0; j < 2; ++j) {
        int row = wn * 32 + j * 16 + lr;
        bfr[j] = *reinterpret_cast<const bf16x8*>(Bs + row * 64 + (((kk << 2) + lg) ^ (row & 7)) * 8);
      }
#pragma unroll
      for (int i = 0; i < 4; ++i)
#pragma unroll
        for (int j = 0; j < 2; ++j)
          acc[i][j] = __builtin_amdgcn_mfma_f32_16x16x32_bf16(af[i], bfr[j], acc[i][j], 0, 0, 0);
    }
    __syncthreads();
  }

#pragma unroll
  for (int i = 0; i < 4; ++i) {
#pragma unroll
    for (int j = 0; j < 2; ++j) {
      int o = on + wn * 32 + j * 16 + lr;
      float bia = bias[o];
#pragma unroll
      for (int r = 0; r < 4; ++r) {
        int t = tm + wm * 64 + i * 16 + lg * 4 + r;
        out[(size_t)t * DIM_ + o] = acc[i][j][r] + bia;
      }
    }
  }
}

// ---------------- flash attention: barrier-free split-K, 32x32x16 MFMA ----------------
// (r11 structure — best measured: 97 us, VGPR 80, occ 26%)
__global__ __launch_bounds__(128, 2)
void attn_kernel(const bf16* __restrict__ qf_g, const bf16* __restrict__ kf_g,
                 const bf16* __restrict__ vf_g, const float* __restrict__ mask6,
                 bf16* __restrict__ ab) {
  __shared__ char smem[16640];   // [O1 16KB][m1 128B][l1 128B]

  const int tid = threadIdx.x;
  const int l = tid & 63;
  const int w = tid >> 6;        // key-half
  const int kl = l & 31, hi = l >> 5;
  const int bid = blockIdx.x;
  const int bh = bid % 24;       // all q-tiles of a head on one XCD class
  const int qt = bid / 24;       // 0..63
  const int h = bh % H_;
  const int b = bh / H_;
  const int q0 = qt * 32;
  const int loff = l * 8;
  const float hm = mask6[h];

  if (hm == 0.0f) {
    bf16x8 z = __builtin_bit_cast(bf16x8, u32x4{0u, 0u, 0u, 0u});
    int row = tid >> 2, c0 = (tid & 3) * 32;
    bf16* dst = ab + ((size_t)b * SEQ_ + q0 + row) * DIM_ + h * HD_ + c0;
#pragma unroll
    for (int u = 0; u < 4; ++u)
      *reinterpret_cast<bf16x8*>(dst + u * 8) = z;
    return;
  }

  float* OM  = (float*)smem;           // [32 q][128 d]
  float* MLm = (float*)(smem + 16384);
  float* MLl = MLm + 32;

  const bf16* qq = qf_g + (((size_t)bh * 64 + qt) * 8) * 512;
  const bf16* kq = kf_g + (size_t)bh * 262144 + (size_t)w * 32 * 4096;
  const bf16* vq = vf_g + (size_t)bh * 262144 + (size_t)w * 32 * 4096;

  bf16x8 qf[8];
#pragma unroll
  for (int kc = 0; kc < 8; ++kc)
    qf[kc] = *reinterpret_cast<const bf16x8*>(qq + kc * 512 + loff);

  f32x16 oacc[4];
#pragma unroll
  for (int df = 0; df < 4; ++df)
#pragma unroll
    for (int r = 0; r < 16; ++r) oacc[df][r] = 0.f;
  float m_lane = -3.0e38f;
  float lsum = 0.f;

  for (int jj = 0; jj < 32; ++jj) {
    const bf16* kb = kq + (size_t)jj * 4096;
    const bf16* vb = vq + (size_t)jj * 4096;

    f32x16 sacc;
#pragma unroll
    for (int r = 0; r < 16; ++r) sacc[r] = 0.f;
    __builtin_amdgcn_s_setprio(1);
#pragma unroll
    for (int kc = 0; kc < 8; ++kc) {
      bf16x8 kfr = *reinterpret_cast<const bf16x8*>(kb + kc * 512 + loff);
      sacc = __builtin_amdgcn_mfma_f32_32x32x16_bf16(kfr, qf[kc], sacc, 0, 0, 0);
    }
    __builtin_amdgcn_s_setprio(0);

    float t = sacc[0];
#pragma unroll
    for (int r = 1; r < 16; ++r) t = fmaxf(t, sacc[r]);
    t = fmaxf(t, __shfl_xor(t, 32));
    bool need = t > m_lane + 8.0f;
    if (__ballot(need) != 0ull) {
      float nm = fmaxf(m_lane, t);
      float c = exp2f(m_lane - nm);
      m_lane = nm;
      lsum *= c;
#pragma unroll
      for (int r = 0; r < 16; ++r) {
        float cr = __shfl(c, (r & 3) + 8 * (r >> 2) + 4 * hi);
#pragma unroll
        for (int df = 0; df < 4; ++df) oacc[df][r] *= cr;
      }
    }

    u32 pp[8];
#pragma unroll
    for (int m = 0; m < 8; ++m) {
      float e0 = exp2f(sacc[2 * m] - m_lane);
      float e1 = exp2f(sacc[2 * m + 1] - m_lane);
      lsum += e0 + e1;
      union { u32 u; bf16 hh2[2]; } pk;
      pk.hh2[0] = (bf16)e0; pk.hh2[1] = (bf16)e1;
      pp[m] = pk.u;
    }

    u32x4 afv[2];
#pragma unroll
    for (int ks = 0; ks < 2; ++ks) {
#pragma unroll
      for (int i = 0; i < 2; ++i) {
        u32 a = pp[4 * ks + i];
        u32 b2 = pp[4 * ks + 2 + i];
        asm volatile("v_permlane32_swap_b32 %0, %1" : "+v"(a), "+v"(b2));
        afv[ks][i] = a;
        afv[ks][2 + i] = b2;
      }
    }

    __builtin_amdgcn_s_setprio(1);
#pragma unroll
    for (int ks = 0; ks < 2; ++ks) {
      bf16x8 pa = __builtin_bit_cast(bf16x8, afv[ks]);
#pragma unroll
      for (int df = 0; df < 4; ++df) {
        bf16x8 vfr = *reinterpret_cast<const bf16x8*>(vb + (ks * 4 + df) * 512 + loff);
        oacc[df] = __builtin_amdgcn_mfma_f32_32x32x16_bf16(pa, vfr, oacc[df], 0, 0, 0);
      }
    }
    __builtin_amdgcn_s_setprio(0);
  }

  float lt = lsum + __shfl_xor(lsum, 32);

  if (w == 1) {
#pragma unroll
    for (int r = 0; r < 16; ++r) {
      int qloc = (r & 3) + 8 * (r >> 2) + 4 * hi;
#pragma unroll
      for (int df = 0; df < 4; ++df)
        OM[qloc * 128 + df * 32 + kl] = oacc[df][r];
    }
    MLm[kl] = m_lane;
    MLl[kl] = lt;
  }
  __syncthreads();
  if (w == 1) return;

  float m1 = MLm[kl];
  float l1 = MLl[kl];
  float M = fmaxf(m_lane, m1);
  float a0 = exp2f(m_lane - M), a1 = exp2f(m1 - M);
  float L = lt * a0 + l1 * a1;
  float s0 = a0 * hm / L, s1 = a1 * hm / L;

#pragma unroll
  for (int r = 0; r < 16; ++r) {
    int qloc = (r & 3) + 8 * (r >> 2) + 4 * hi;
    float r0 = __shfl(s0, qloc);
    float r1 = __shfl(s1, qloc);
    int n = q0 + qloc;
#pragma unroll
    for (int df = 0; df < 4; ++df) {
      int d = df * 32 + kl;
      float o1 = OM[qloc * 128 + df * 32 + kl];
      ab[((size_t)b * SEQ_ + n) * DIM_ + h * HD_ + d] =
          (bf16)(oacc[df][r] * r0 + o1 * r1);
    }
  }
}

extern "C" void kernel_launch(void* const* d_in, const int* in_sizes, int n_in,
                              void* d_out, int out_size, void* d_ws, size_t ws_size,
                              hipStream_t stream) {
  const float* x        = (const float*)d_in[0];
  const float* latency  = (const float*)d_in[1];
  const float* qkv_w    = (const float*)d_in[2];
  const float* qkv_b    = (const float*)d_in[3];
  const float* proj_w   = (const float*)d_in[4];
  const float* proj_b   = (const float*)d_in[5];
  const float* router_w = (const float*)d_in[6];
  const float* router_b = (const float*)d_in[7];
  const float* g1       = (const float*)d_in[8];
  const float* g2       = (const float*)d_in[9];
  float* out = (float*)d_out;

  const size_t N_X  = (size_t)TOK_ * DIM_;
  const size_t N_WQ = (size_t)OUT3_ * DIM_;
  const size_t N_WP = (size_t)DIM_ * DIM_;
  const size_t N_P  = (size_t)NB_ * H_ * SEQ_ * HD_;

  float* maskp = (float*)d_ws;
  bf16* xb  = (bf16*)((char*)d_ws + 256);
  bf16* wqb = xb + N_X;
  bf16* wpb = wqb + N_WQ;
  bf16* qbf = wpb + N_WP;
  bf16* kbf = qbf + N_P;
  bf16* vtb = kbf + N_P;
  bf16* abf = vtb + N_P;

  size_t need = 256 + 2 * (N_X + N_WQ + N_WP + 4 * N_P);
  if (ws_size < need) return;

  const int prep_blocks = (int)((N_X + N_WQ + N_WP) / 1024);   // 8448
  prep_kernel<<<prep_blocks, 256, 0, stream>>>(x, qkv_w, proj_w, latency, router_w,
                                               router_b, g1, g2, xb, wqb, wpb, maskp);

  qkv_gemm<<<dim3(OUT3_ / 128, TOK_ / 128), 256, 0, stream>>>(xb, wqb, qkv_b, maskp, qbf, kbf, vtb);
  attn_kernel<<<dim3(24 * (SEQ_ / 32)), 128, 0, stream>>>(qbf, kbf, vtb, maskp, abf);
  proj_gemm<<<dim3(DIM_ / 64, TOK_ / 128), 256, 0, stream>>>(abf, wpb, proj_b, out);
}